// Round 10
// baseline (390.451 us; speedup 1.0000x reference)
//
#include <hip/hip_runtime.h>
#include <math.h>

// Problem constants (from reference): B=4, SQ=SP=2048, H=256
#define BB 4
#define SS 2048
#define HH 256
#define NEG_BIG -1e9f
#define GSEG ((size_t)BB * SS * 5 * HH)  // elements per output tensor
#define NT ((size_t)BB * SS * HH)        // elements per E-like tensor

typedef unsigned short ushort_t;
typedef __attribute__((ext_vector_type(8))) __bf16 bf16x8;
typedef __attribute__((ext_vector_type(8))) unsigned short ushort8;
typedef __attribute__((ext_vector_type(4))) float f32x4;

// split fp32 into bf16 hi + bf16 lo (RNE both)
__device__ __forceinline__ void bsplit(float x, ushort_t& hi, ushort_t& lo) {
  union { float f; unsigned u; } a; a.f = x;
  unsigned r = a.u + 0x7FFFu + ((a.u >> 16) & 1u);
  ushort_t h = (ushort_t)(r >> 16);
  union { unsigned u; float f; } hf; hf.u = ((unsigned)h) << 16;
  float l = x - hf.f;
  union { float f; unsigned u; } b; b.f = l;
  unsigned r2 = b.u + 0x7FFFu + ((b.u >> 16) & 1u);
  hi = h; lo = (ushort_t)(r2 >> 16);
}

// ------------------------------------------------------------------
// K0: sp[b,p] = dot(E_p[b,p,:], w_p);  sq[b,q] = dot(E_q[b,q,:], w_q)
// ------------------------------------------------------------------
__global__ __launch_bounds__(256) void k_rowdots(
    const float* __restrict__ Eq, const float* __restrict__ Ep,
    const float* __restrict__ W,
    float* __restrict__ sqv, float* __restrict__ spv) {
  int g = blockIdx.x * 256 + threadIdx.x;
  int wid = g >> 6;
  int lane = g & 63;
  const int total = BB * SS;
  int isp = wid >= total;
  int row = isp ? (wid - total) : wid;
  const float* Er = (isp ? Ep : Eq) + (size_t)row * HH;
  const float* w = W + (isp ? HH : 0);
  float4 e = ((const float4*)Er)[lane];
  float4 wv = ((const float4*)w)[lane];
  float acc = e.x * wv.x + e.y * wv.y + e.z * wv.z + e.w * wv.w;
#pragma unroll
  for (int off = 32; off > 0; off >>= 1) acc += __shfl_down(acc, off, 64);
  if (lane == 0) (isp ? spv : sqv)[row] = acc;
}

// ------------------------------------------------------------------
// K_rc: row-major split convert. src fp32 [b][r][h] (* optional wm[h])
//       -> dh/dl bf16 [b][r][h]. 8 elements/thread.
// ------------------------------------------------------------------
__global__ __launch_bounds__(256) void k_rc(
    const float* __restrict__ src, const float* __restrict__ wm,
    ushort_t* __restrict__ dh, ushort_t* __restrict__ dl) {
  size_t i = ((size_t)blockIdx.x * 256 + threadIdx.x) * 8;
  float4 v0 = *(const float4*)(src + i);
  float4 v1 = *(const float4*)(src + i + 4);
  if (wm) {
    int h = (int)(i & (HH - 1));
    float4 w0 = *(const float4*)(wm + h);
    float4 w1 = *(const float4*)(wm + h + 4);
    v0.x *= w0.x; v0.y *= w0.y; v0.z *= w0.z; v0.w *= w0.w;
    v1.x *= w1.x; v1.y *= w1.y; v1.z *= w1.z; v1.w *= w1.w;
  }
  ushort8 h8, l8;
  ushort_t hh, ll;
  bsplit(v0.x, hh, ll); h8[0] = hh; l8[0] = ll;
  bsplit(v0.y, hh, ll); h8[1] = hh; l8[1] = ll;
  bsplit(v0.z, hh, ll); h8[2] = hh; l8[2] = ll;
  bsplit(v0.w, hh, ll); h8[3] = hh; l8[3] = ll;
  bsplit(v1.x, hh, ll); h8[4] = hh; l8[4] = ll;
  bsplit(v1.y, hh, ll); h8[5] = hh; l8[5] = ll;
  bsplit(v1.z, hh, ll); h8[6] = hh; l8[6] = ll;
  bsplit(v1.w, hh, ll); h8[7] = hh; l8[7] = ll;
  *(ushort8*)(dh + i) = h8;
  *(ushort8*)(dl + i) = l8;
}

// ------------------------------------------------------------------
// K_tc: transpose-convert  src fp32 [b][r<SS][h<HH]  ->  dhi/dlo bf16 [b][h][r]
// ------------------------------------------------------------------
__global__ __launch_bounds__(256) void k_tc(
    const float* __restrict__ src, ushort_t* __restrict__ dhi, ushort_t* __restrict__ dlo) {
  __shared__ float tile[64][65];
  int b = blockIdx.z;
  int r0 = blockIdx.x << 6;
  int h0 = blockIdx.y << 6;
  int tid = threadIdx.x;
  int rl = tid >> 4, c4 = (tid & 15) << 2;
  size_t srcb = (size_t)b * SS * HH;
#pragma unroll
  for (int i = 0; i < 4; ++i) {
    float4 v = *(const float4*)(src + srcb + (size_t)(r0 + rl + 16 * i) * HH + h0 + c4);
    tile[rl + 16 * i][c4 + 0] = v.x;
    tile[rl + 16 * i][c4 + 1] = v.y;
    tile[rl + 16 * i][c4 + 2] = v.z;
    tile[rl + 16 * i][c4 + 3] = v.w;
  }
  __syncthreads();
  size_t dstb = (size_t)b * HH;
#pragma unroll
  for (int i = 0; i < 4; ++i) {
    int h = rl + 16 * i;
    ushort4 h4, l4;
    ushort_t hh, ll;
    bsplit(tile[c4 + 0][h], hh, ll); h4.x = hh; l4.x = ll;
    bsplit(tile[c4 + 1][h], hh, ll); h4.y = hh; l4.y = ll;
    bsplit(tile[c4 + 2][h], hh, ll); h4.z = hh; l4.z = ll;
    bsplit(tile[c4 + 3][h], hh, ll); h4.w = hh; l4.w = ll;
    size_t o = (dstb + h0 + h) * SS + r0 + c4;
    *(ushort4*)(dhi + o) = h4;
    *(ushort4*)(dlo + o) = l4;
  }
}

// ------------------------------------------------------------------
// K1 (MFMA): U[b,p,q] = sum_h (Ep*wm)[p,h]*Eq[q,h] + sp[p] + sq[q], masked.
// (HW-validated round 9: 358us total, k_trim not in top-5)
// ------------------------------------------------------------------
__global__ __launch_bounds__(512, 4) void k_trim(
    const ushort_t* __restrict__ Ah_g, const ushort_t* __restrict__ Al_g,  // (Ep*wm) split
    const ushort_t* __restrict__ Bh_g, const ushort_t* __restrict__ Bl_g,  // Eq split
    const float* __restrict__ m1, const float* __restrict__ m2,
    const float* __restrict__ spv, const float* __restrict__ sqv,
    float* __restrict__ U) {
  __shared__ ushort_t Ash[32 * 64];   // 4 KB
  __shared__ ushort_t Asl[32 * 64];   // 4 KB
  __shared__ ushort_t Bsh[256 * 64];  // 32 KB
  __shared__ ushort_t Bsl[256 * 64];  // 32 KB
  int b = blockIdx.z;
  int q0 = blockIdx.x << 8;  // 256-wide q tile
  int p0 = blockIdx.y << 5;  // 32-wide p tile
  int tid = threadIdx.x;
  size_t bS = (size_t)b * SS;

  int w = tid >> 6, l = tid & 63;
  int wr = w >> 2, wc = w & 3;          // 2x4 wave grid
  int arow = wr * 16 + (l & 15);        // A-frag p row 0..31
  unsigned asw = ((unsigned)(arow & 7)) << 4;
  int lk8 = (l >> 4) << 3;              // k sub-offset (0,8,16,24)
  int qcl = wc * 64 + (l & 15);         // B-frag q col base (plus cf*16)

  f32x4 acc[4];
#pragma unroll
  for (int i = 0; i < 4; ++i) acc[i] = (f32x4){0.f, 0.f, 0.f, 0.f};

  char* AshB = (char*)Ash;
  char* AslB = (char*)Asl;
  char* BshB = (char*)Bsh;
  char* BslB = (char*)Bsl;

  for (int k0 = 0; k0 < HH; k0 += 64) {
    // stage A: 32 p-rows x 64 h (256 threads, ushort8 each)
    if (tid < 256) {
      int row = tid >> 3;
      int k8 = (tid & 7) << 3;
      unsigned off = ((unsigned)(row * 128 + k8 * 2)) ^ (((unsigned)(row & 7)) << 4);
      size_t g = (bS + p0 + row) * HH + k0 + k8;
      *(ushort8*)(AshB + off) = *(const ushort8*)(Ah_g + g);
      *(ushort8*)(AslB + off) = *(const ushort8*)(Al_g + g);
    }
    // stage B: 256 q-rows x 64 h
#pragma unroll
    for (int i = 0; i < 4; ++i) {
      int idx = tid + i * 512;
      int row = idx >> 3;
      int k8 = (idx & 7) << 3;
      unsigned off = ((unsigned)(row * 128 + k8 * 2)) ^ (((unsigned)(row & 7)) << 4);
      size_t g = (bS + q0 + row) * HH + k0 + k8;
      *(ushort8*)(BshB + off) = *(const ushort8*)(Bh_g + g);
      *(ushort8*)(BslB + off) = *(const ushort8*)(Bl_g + g);
    }
    __syncthreads();
#pragma unroll
    for (int kc = 0; kc < 64; kc += 32) {
      int ak = kc + lk8;
      unsigned aoff = ((unsigned)(arow * 128 + ak * 2)) ^ asw;
      bf16x8 ah = *(const bf16x8*)(AshB + aoff);
      bf16x8 al = *(const bf16x8*)(AslB + aoff);
#pragma unroll
      for (int cf = 0; cf < 4; ++cf) {
        int r = qcl + cf * 16;
        unsigned boff = ((unsigned)(r * 128 + ak * 2)) ^ (((unsigned)(r & 7)) << 4);
        bf16x8 bh = *(const bf16x8*)(BshB + boff);
        bf16x8 bl = *(const bf16x8*)(BslB + boff);
        acc[cf] = __builtin_amdgcn_mfma_f32_16x16x32_bf16(ah, bh, acc[cf], 0, 0, 0);
        acc[cf] = __builtin_amdgcn_mfma_f32_16x16x32_bf16(ah, bl, acc[cf], 0, 0, 0);
        acc[cf] = __builtin_amdgcn_mfma_f32_16x16x32_bf16(al, bh, acc[cf], 0, 0, 0);
      }
    }
    __syncthreads();
  }

  // epilogue: + sp + sq, mask, store U
  int crow = wr * 16 + ((l >> 4) << 2);  // + j
  float spr[4], mpr[4];
#pragma unroll
  for (int j = 0; j < 4; ++j) {
    spr[j] = spv[bS + p0 + crow + j];
    mpr[j] = m1[bS + p0 + crow + j];
  }
#pragma unroll
  for (int cf = 0; cf < 4; ++cf) {
    int q = q0 + qcl + cf * 16;
    float sqc = sqv[bS + q];
    float mqc = m2[bS + q];
#pragma unroll
    for (int j = 0; j < 4; ++j) {
      int p = p0 + crow + j;
      float v = acc[cf][j] + spr[j] + sqc;
      if (mpr[j] * mqc < 0.5f) v = NEG_BIG;
      U[(bS + p) * SS + q] = v;
    }
  }
}

// ------------------------------------------------------------------
// K2: row softmax stats (axis=2, over q)
// ------------------------------------------------------------------
__global__ __launch_bounds__(256) void k_rowstats(
    const float* __restrict__ U, float* __restrict__ rowmax, float* __restrict__ rowinv) {
  __shared__ float redm[4];
  __shared__ float reds[4];
  int row = blockIdx.x;
  int tid = threadIdx.x;
  const float* u = U + (size_t)row * SS;
  float4 v1 = ((const float4*)u)[tid];
  float4 v2 = ((const float4*)u)[tid + 256];
  float m = fmaxf(fmaxf(fmaxf(v1.x, v1.y), fmaxf(v1.z, v1.w)),
                  fmaxf(fmaxf(v2.x, v2.y), fmaxf(v2.z, v2.w)));
#pragma unroll
  for (int off = 32; off > 0; off >>= 1) m = fmaxf(m, __shfl_down(m, off, 64));
  if ((tid & 63) == 0) redm[tid >> 6] = m;
  __syncthreads();
  m = fmaxf(fmaxf(redm[0], redm[1]), fmaxf(redm[2], redm[3]));
  float s = __expf(v1.x - m) + __expf(v1.y - m) + __expf(v1.z - m) + __expf(v1.w - m)
          + __expf(v2.x - m) + __expf(v2.y - m) + __expf(v2.z - m) + __expf(v2.w - m);
#pragma unroll
  for (int off = 32; off > 0; off >>= 1) s += __shfl_down(s, off, 64);
  if ((tid & 63) == 0) reds[tid >> 6] = s;
  __syncthreads();
  if (tid == 0) {
    float st = reds[0] + reds[1] + reds[2] + reds[3];
    rowmax[row] = m;
    rowinv[row] = 1.0f / st;
  }
}

// ------------------------------------------------------------------
// K3a/K3b: column softmax stats (axis=1, over p)
// ------------------------------------------------------------------
__global__ __launch_bounds__(256) void k_colpart(
    const float* __restrict__ U, float* __restrict__ pm, float* __restrict__ ps) {
  int q = blockIdx.x * 256 + threadIdx.x;
  int pc = blockIdx.y;
  int b = blockIdx.z;
  const float* u = U + ((size_t)b * SS + pc * 128) * SS + q;
  float m = -INFINITY, s = 0.f;
  for (int p = 0; p < 128; ++p) {
    float x = u[(size_t)p * SS];
    float nm = fmaxf(m, x);
    s = s * __expf(m - nm) + __expf(x - nm);
    m = nm;
  }
  int o = (pc * BB + b) * SS + q;
  pm[o] = m;
  ps[o] = s;
}

__global__ __launch_bounds__(256) void k_colcomb(
    const float* __restrict__ pm, const float* __restrict__ ps,
    float* __restrict__ colmax, float* __restrict__ colinv) {
  int i = blockIdx.x * 256 + threadIdx.x;
  float m = -INFINITY;
#pragma unroll
  for (int pc = 0; pc < 16; ++pc) m = fmaxf(m, pm[(size_t)pc * BB * SS + i]);
  float s = 0.f;
#pragma unroll
  for (int pc = 0; pc < 16; ++pc)
    s += ps[(size_t)pc * BB * SS + i] * __expf(pm[(size_t)pc * BB * SS + i] - m);
  colmax[i] = m;
  colinv[i] = 1.0f / s;
}

// ------------------------------------------------------------------
// MFMA level kernels: Out[r,h] = sum_k exp(U - max) * E[k,h]
// ROUND 10: tile 64 rows x 256 h, 1024 thr = 16 waves (4x4 grid).
// B-panel staged once per 64 rows (was per 32) -> staging bytes per
// output halve; per-iter staged bytes 48KB/32-row-equiv (was 80KB).
// LDS 80KB: P 16KB + B 64KB. Grid (SS/64, 2, BB) = 256 blocks = 1/CU,
// 16 waves/CU. Fragment plumbing byte-identical to HW-validated r6/r9.
// ------------------------------------------------------------------
template <int LEVEL>
__global__ __launch_bounds__(1024, 4) void k_level(
    const float* __restrict__ U,
    const ushort_t* __restrict__ B0h, const ushort_t* __restrict__ B0l,
    const ushort_t* __restrict__ B1h, const ushort_t* __restrict__ B1l,
    const float* __restrict__ rowmax, const float* __restrict__ rowinv,
    const float* __restrict__ colmax, const float* __restrict__ colinv,
    const float* __restrict__ Eq, const float* __restrict__ Ep,
    float* __restrict__ A1w, float* __restrict__ B1w,
    float* __restrict__ out) {
  __shared__ ushort_t Ph[64 * 64];    // 8 KB
  __shared__ ushort_t Pl[64 * 64];    // 8 KB
  __shared__ ushort_t Bsh[256 * 64];  // 32 KB
  __shared__ ushort_t Bsl[256 * 64];  // 32 KB
  int b = blockIdx.z;
  int mode = blockIdx.y;
  int r0 = blockIdx.x << 6;       // 64-row tile
  int tid = threadIdx.x;
  size_t bS = (size_t)b * SS;
  const float* Ub = U + bS * SS;
  const ushort_t* Bh = (mode == 0 ? B0h : B1h) + (size_t)b * HH * SS;
  const ushort_t* Bl = (mode == 0 ? B0l : B1l) + (size_t)b * HH * SS;

  int srow0 = tid >> 4;           // mode0: p row 0..63
  int sc40 = (tid & 15) << 2;     // mode0: q (k) 0..60
  int srow1 = tid >> 4;           // mode1: p (k) 0..63
  int sc41 = (tid & 15) << 2;     // mode1: q col 0..60
  float rm = 0.f;
  float4 cm4;
  if (mode == 0) rm = rowmax[bS + r0 + srow0];
  else cm4 = *(const float4*)(colmax + bS + r0 + sc41);

  int w = tid >> 6, l = tid & 63;
  int wr = w >> 2, wc = w & 3;          // 4x4 wave grid
  int arow = wr * 16 + (l & 15);        // A-frag row 0..63
  unsigned asw = ((unsigned)(arow & 7)) << 4;
  int lk8 = (l >> 4) << 3;              // k sub-offset (0,8,16,24)
  int hcol = wc * 64 + (l & 15);        // B-frag h (plus cf*16)

  f32x4 acc[4];
#pragma unroll
  for (int i = 0; i < 4; ++i) acc[i] = (f32x4){0.f, 0.f, 0.f, 0.f};

  char* PhB = (char*)Ph;
  char* PlB = (char*)Pl;
  char* BhB = (char*)Bsh;
  char* BlB = (char*)Bsl;

  for (int k0 = 0; k0 < SS; k0 += 64) {
    // ---- stage B^T chunk [256 h][64 k] into swizzled LDS ----
#pragma unroll
    for (int i = 0; i < 2; ++i) {
      int idx = tid + i * 1024;
      int h = idx >> 3;
      int k8 = (idx & 7) << 3;
      unsigned off = ((unsigned)(h * 128 + k8 * 2)) ^ (((unsigned)(h & 7)) << 4);
      *(ushort8*)(BhB + off) = *(const ushort8*)(Bh + (size_t)h * SS + k0 + k8);
      *(ushort8*)(BlB + off) = *(const ushort8*)(Bl + (size_t)h * SS + k0 + k8);
    }
    // ---- stage P tile [64 rows][64 k] (exp + split) into swizzled LDS ----
    if (mode == 0) {
      float4 u4 = *(const float4*)(Ub + (size_t)(r0 + srow0) * SS + k0 + sc40);
      ushort4 h4, l4;
      ushort_t hh, ll;
      bsplit(__expf(u4.x - rm), hh, ll); h4.x = hh; l4.x = ll;
      bsplit(__expf(u4.y - rm), hh, ll); h4.y = hh; l4.y = ll;
      bsplit(__expf(u4.z - rm), hh, ll); h4.z = hh; l4.z = ll;
      bsplit(__expf(u4.w - rm), hh, ll); h4.w = hh; l4.w = ll;
      unsigned off = ((unsigned)(srow0 * 128 + sc40 * 2)) ^ (((unsigned)(srow0 & 7)) << 4);
      *(ushort4*)(PhB + off) = h4;
      *(ushort4*)(PlB + off) = l4;
    } else {
      float4 u4 = *(const float4*)(Ub + (size_t)(k0 + srow1) * SS + r0 + sc41);
      float e[4] = {__expf(u4.x - cm4.x), __expf(u4.y - cm4.y),
                    __expf(u4.z - cm4.z), __expf(u4.w - cm4.w)};
#pragma unroll
      for (int j = 0; j < 4; ++j) {
        ushort_t hh, ll;
        bsplit(e[j], hh, ll);
        int rr = sc41 + j;
        unsigned off = ((unsigned)(rr * 128 + srow1 * 2)) ^ (((unsigned)(rr & 7)) << 4);
        *(ushort_t*)(PhB + off) = hh;
        *(ushort_t*)(PlB + off) = ll;
      }
    }
    __syncthreads();
    // ---- compute: 2 K-chunks of 32 ----
#pragma unroll
    for (int kc = 0; kc < 64; kc += 32) {
      int ak = kc + lk8;
      unsigned aoff = ((unsigned)(arow * 128 + ak * 2)) ^ asw;
      bf16x8 ah = *(const bf16x8*)(PhB + aoff);
      bf16x8 al = *(const bf16x8*)(PlB + aoff);
#pragma unroll
      for (int cf = 0; cf < 4; ++cf) {
        int h = hcol + cf * 16;
        unsigned boff = ((unsigned)(h * 128 + ak * 2)) ^ (((unsigned)(h & 7)) << 4);
        bf16x8 bh = *(const bf16x8*)(BhB + boff);
        bf16x8 bl = *(const bf16x8*)(BlB + boff);
        acc[cf] = __builtin_amdgcn_mfma_f32_16x16x32_bf16(ah, bh, acc[cf], 0, 0, 0);
        acc[cf] = __builtin_amdgcn_mfma_f32_16x16x32_bf16(ah, bl, acc[cf], 0, 0, 0);
        acc[cf] = __builtin_amdgcn_mfma_f32_16x16x32_bf16(al, bh, acc[cf], 0, 0, 0);
      }
    }
    __syncthreads();
  }

  // ---- epilogue ----
  int crow = wr * 16 + ((l >> 4) << 2);  // + j, 0..63
  if (LEVEL == 1) {
    const float* inv = mode == 0 ? rowinv : colinv;
    float* Out = mode == 0 ? A1w : B1w;
#pragma unroll
    for (int j = 0; j < 4; ++j) {
      int rr = r0 + crow + j;
      float sc = inv[bS + rr];
#pragma unroll
      for (int cf = 0; cf < 4; ++cf) {
        int h = hcol + cf * 16;
        Out[(bS + rr) * HH + h] = acc[cf][j] * sc;
      }
    }
  } else {
    if (mode == 0) {
      float* Gqp = out + GSEG;  // rows are p
#pragma unroll
      for (int j = 0; j < 4; ++j) {
        int rr = r0 + crow + j;
        float sc = rowinv[bS + rr];
#pragma unroll
        for (int cf = 0; cf < 4; ++cf) {
          int h = hcol + cf * 16;
          size_t eidx = (bS + rr) * HH + h;
          float a2 = acc[cf][j] * sc;
          float ep = Ep[eidx];
          float a1 = A1w[eidx];
          float* g = Gqp + (bS + rr) * (size_t)(5 * HH) + h;
          g[0 * HH] = ep;
          g[1 * HH] = a1;
          g[2 * HH] = a2;
          g[3 * HH] = ep * a1;
          g[4 * HH] = ep * a2;
        }
      }
    } else {
#pragma unroll
      for (int j = 0; j < 4; ++j) {
        int rr = r0 + crow + j;
        float sc = colinv[bS + rr];
#pragma unroll
        for (int cf = 0; cf < 4; ++cf) {
          int h = hcol + cf * 16;
          size_t eidx = (bS + rr) * HH + h;
          float b2 = acc[cf][j] * sc;
          float eq = Eq[eidx];
          float b1 = B1w[eidx];
          float* g = out + (bS + rr) * (size_t)(5 * HH) + h;
          g[0 * HH] = eq;
          g[1 * HH] = b1;
          g[2 * HH] = b2;
          g[3 * HH] = eq * b1;
          g[4 * HH] = eq * b2;
        }
      }
    }
  }
}

// ------------------------------------------------------------------
extern "C" void kernel_launch(void* const* d_in, const int* in_sizes, int n_in,
                              void* d_out, int out_size, void* d_ws, size_t ws_size,
                              hipStream_t stream) {
  const float* Eq = (const float*)d_in[0];
  const float* Ep = (const float*)d_in[1];
  const float* m1 = (const float*)d_in[2];
  const float* m2 = (const float*)d_in[3];
  const float* W  = (const float*)d_in[4];
  float* out = (float*)d_out;

  // workspace layout (~96 MB — matches the HW-proven round-3/6/9 footprint)
  float* ws     = (float*)d_ws;
  float* U      = ws;                              // B*S*S fp32 (64 MB)
  float* rowmax = U + (size_t)BB * SS * SS;
  float* rowinv = rowmax + BB * SS;
  float* colmax = rowinv + BB * SS;
  float* colinv = colmax + BB * SS;
  float* spv    = colinv + BB * SS;
  float* sqv    = spv + BB * SS;
  float* A1w    = sqv + BB * SS;                   // B*S*H fp32 (8 MB)
  float* B1w    = A1w + NT;                        // B*S*H fp32 (8 MB)
  ushort_t* EqTh = (ushort_t*)(B1w + NT);          // 4 x (B*H*S) bf16 (16 MB)
  ushort_t* EqTl = EqTh + NT;
  ushort_t* EpTh = EqTl + NT;
  ushort_t* EpTl = EpTh + NT;
  // Row-major split tensors alias A1w/B1w: consumed only by k_trim, which
  // runs before anything writes A1w/B1w. EqRh+EqRl (8MB) == A1w's 8MB.
  ushort_t* EqRh = (ushort_t*)A1w;
  ushort_t* EqRl = EqRh + NT;
  ushort_t* ApRh = (ushort_t*)B1w;
  ushort_t* ApRl = ApRh + NT;
  // pm/ps also alias A1w: written by k_colpart AFTER k_trim (EqR dead),
  // dead after k_colcomb, before k_level<1> writes A1w.
  float* pm     = A1w;
  float* ps     = pm + 16 * BB * SS;
  // A1T/B1T alias EqT/EpT storage: EqT/EpT dead after k_level<1>
  ushort_t* A1Th = EqTh;
  ushort_t* A1Tl = EqTl;
  ushort_t* B1Th = EpTh;
  ushort_t* B1Tl = EpTl;

  dim3 tcg(SS / 64, HH / 64, BB);

  k_rowdots<<<2 * BB * SS / 4, 256, 0, stream>>>(Eq, Ep, W, sqv, spv);
  k_rc<<<(int)(NT / 2048), 256, 0, stream>>>(Eq, nullptr, EqRh, EqRl);
  k_rc<<<(int)(NT / 2048), 256, 0, stream>>>(Ep, W + 2 * HH, ApRh, ApRl);
  k_tc<<<tcg, 256, 0, stream>>>(Eq, EqTh, EqTl);
  k_tc<<<tcg, 256, 0, stream>>>(Ep, EpTh, EpTl);
  k_trim<<<dim3(SS / 256, SS / 32, BB), 512, 0, stream>>>(
      ApRh, ApRl, EqRh, EqRl, m1, m2, spv, sqv, U);
  k_rowstats<<<BB * SS, 256, 0, stream>>>(U, rowmax, rowinv);
  k_colpart<<<dim3(SS / 256, 16, BB), 256, 0, stream>>>(U, pm, ps);
  k_colcomb<<<BB * SS / 256, 256, 0, stream>>>(pm, ps, colmax, colinv);
  k_level<1><<<dim3(SS / 64, 2, BB), 1024, 0, stream>>>(
      U, EqTh, EqTl, EpTh, EpTl, rowmax, rowinv, colmax, colinv,
      Eq, Ep, A1w, B1w, out);
  k_tc<<<tcg, 256, 0, stream>>>(A1w, A1Th, A1Tl);
  k_tc<<<tcg, 256, 0, stream>>>(B1w, B1Th, B1Tl);
  k_level<2><<<dim3(SS / 64, 2, BB), 1024, 0, stream>>>(
      U, B1Th, B1Tl, A1Th, A1Tl, rowmax, rowinv, colmax, colinv,
      Eq, Ep, A1w, B1w, out);
}

// Round 11
// 362.404 us; speedup vs baseline: 1.0774x; 1.0774x over previous
//
#include <hip/hip_runtime.h>
#include <math.h>

// Problem constants (from reference): B=4, SQ=SP=2048, H=256
#define BB 4
#define SS 2048
#define HH 256
#define NEG_BIG -1e9f
#define GSEG ((size_t)BB * SS * 5 * HH)  // elements per output tensor
#define NT ((size_t)BB * SS * HH)        // elements per E-like tensor

typedef unsigned short ushort_t;
typedef __attribute__((ext_vector_type(8))) __bf16 bf16x8;
typedef __attribute__((ext_vector_type(8))) unsigned short ushort8;
typedef __attribute__((ext_vector_type(4))) float f32x4;

// split fp32 into bf16 hi + bf16 lo (RNE both)
__device__ __forceinline__ void bsplit(float x, ushort_t& hi, ushort_t& lo) {
  union { float f; unsigned u; } a; a.f = x;
  unsigned r = a.u + 0x7FFFu + ((a.u >> 16) & 1u);
  ushort_t h = (ushort_t)(r >> 16);
  union { unsigned u; float f; } hf; hf.u = ((unsigned)h) << 16;
  float l = x - hf.f;
  union { float f; unsigned u; } b; b.f = l;
  unsigned r2 = b.u + 0x7FFFu + ((b.u >> 16) & 1u);
  hi = h; lo = (ushort_t)(r2 >> 16);
}

// ------------------------------------------------------------------
// K0: sp[b,p] = dot(E_p[b,p,:], w_p);  sq[b,q] = dot(E_q[b,q,:], w_q)
// ------------------------------------------------------------------
__global__ __launch_bounds__(256) void k_rowdots(
    const float* __restrict__ Eq, const float* __restrict__ Ep,
    const float* __restrict__ W,
    float* __restrict__ sqv, float* __restrict__ spv) {
  int g = blockIdx.x * 256 + threadIdx.x;
  int wid = g >> 6;
  int lane = g & 63;
  const int total = BB * SS;
  int isp = wid >= total;
  int row = isp ? (wid - total) : wid;
  const float* Er = (isp ? Ep : Eq) + (size_t)row * HH;
  const float* w = W + (isp ? HH : 0);
  float4 e = ((const float4*)Er)[lane];
  float4 wv = ((const float4*)w)[lane];
  float acc = e.x * wv.x + e.y * wv.y + e.z * wv.z + e.w * wv.w;
#pragma unroll
  for (int off = 32; off > 0; off >>= 1) acc += __shfl_down(acc, off, 64);
  if (lane == 0) (isp ? spv : sqv)[row] = acc;
}

// ------------------------------------------------------------------
// K_rc: row-major split convert. src fp32 [b][r][h] (* optional wm[h])
//       -> dh/dl bf16 [b][r][h]. 8 elements/thread.
// ------------------------------------------------------------------
__global__ __launch_bounds__(256) void k_rc(
    const float* __restrict__ src, const float* __restrict__ wm,
    ushort_t* __restrict__ dh, ushort_t* __restrict__ dl) {
  size_t i = ((size_t)blockIdx.x * 256 + threadIdx.x) * 8;
  float4 v0 = *(const float4*)(src + i);
  float4 v1 = *(const float4*)(src + i + 4);
  if (wm) {
    int h = (int)(i & (HH - 1));
    float4 w0 = *(const float4*)(wm + h);
    float4 w1 = *(const float4*)(wm + h + 4);
    v0.x *= w0.x; v0.y *= w0.y; v0.z *= w0.z; v0.w *= w0.w;
    v1.x *= w1.x; v1.y *= w1.y; v1.z *= w1.z; v1.w *= w1.w;
  }
  ushort8 h8, l8;
  ushort_t hh, ll;
  bsplit(v0.x, hh, ll); h8[0] = hh; l8[0] = ll;
  bsplit(v0.y, hh, ll); h8[1] = hh; l8[1] = ll;
  bsplit(v0.z, hh, ll); h8[2] = hh; l8[2] = ll;
  bsplit(v0.w, hh, ll); h8[3] = hh; l8[3] = ll;
  bsplit(v1.x, hh, ll); h8[4] = hh; l8[4] = ll;
  bsplit(v1.y, hh, ll); h8[5] = hh; l8[5] = ll;
  bsplit(v1.z, hh, ll); h8[6] = hh; l8[6] = ll;
  bsplit(v1.w, hh, ll); h8[7] = hh; l8[7] = ll;
  *(ushort8*)(dh + i) = h8;
  *(ushort8*)(dl + i) = l8;
}

// ------------------------------------------------------------------
// K_tc: transpose-convert  src fp32 [b][r<SS][h<HH]  ->  dhi/dlo bf16 [b][h][r]
// ------------------------------------------------------------------
__global__ __launch_bounds__(256) void k_tc(
    const float* __restrict__ src, ushort_t* __restrict__ dhi, ushort_t* __restrict__ dlo) {
  __shared__ float tile[64][65];
  int b = blockIdx.z;
  int r0 = blockIdx.x << 6;
  int h0 = blockIdx.y << 6;
  int tid = threadIdx.x;
  int rl = tid >> 4, c4 = (tid & 15) << 2;
  size_t srcb = (size_t)b * SS * HH;
#pragma unroll
  for (int i = 0; i < 4; ++i) {
    float4 v = *(const float4*)(src + srcb + (size_t)(r0 + rl + 16 * i) * HH + h0 + c4);
    tile[rl + 16 * i][c4 + 0] = v.x;
    tile[rl + 16 * i][c4 + 1] = v.y;
    tile[rl + 16 * i][c4 + 2] = v.z;
    tile[rl + 16 * i][c4 + 3] = v.w;
  }
  __syncthreads();
  size_t dstb = (size_t)b * HH;
#pragma unroll
  for (int i = 0; i < 4; ++i) {
    int h = rl + 16 * i;
    ushort4 h4, l4;
    ushort_t hh, ll;
    bsplit(tile[c4 + 0][h], hh, ll); h4.x = hh; l4.x = ll;
    bsplit(tile[c4 + 1][h], hh, ll); h4.y = hh; l4.y = ll;
    bsplit(tile[c4 + 2][h], hh, ll); h4.z = hh; l4.z = ll;
    bsplit(tile[c4 + 3][h], hh, ll); h4.w = hh; l4.w = ll;
    size_t o = (dstb + h0 + h) * SS + r0 + c4;
    *(ushort4*)(dhi + o) = h4;
    *(ushort4*)(dlo + o) = l4;
  }
}

// ------------------------------------------------------------------
// K1 (MFMA): U[b,p,q] = sum_h (Ep*wm)[p,h]*Eq[q,h] + sp[p] + sq[q], masked.
// (HW-validated round 9: not in top-5)
// ------------------------------------------------------------------
__global__ __launch_bounds__(512, 4) void k_trim(
    const ushort_t* __restrict__ Ah_g, const ushort_t* __restrict__ Al_g,  // (Ep*wm) split
    const ushort_t* __restrict__ Bh_g, const ushort_t* __restrict__ Bl_g,  // Eq split
    const float* __restrict__ m1, const float* __restrict__ m2,
    const float* __restrict__ spv, const float* __restrict__ sqv,
    float* __restrict__ U) {
  __shared__ ushort_t Ash[32 * 64];   // 4 KB
  __shared__ ushort_t Asl[32 * 64];   // 4 KB
  __shared__ ushort_t Bsh[256 * 64];  // 32 KB
  __shared__ ushort_t Bsl[256 * 64];  // 32 KB
  int b = blockIdx.z;
  int q0 = blockIdx.x << 8;  // 256-wide q tile
  int p0 = blockIdx.y << 5;  // 32-wide p tile
  int tid = threadIdx.x;
  size_t bS = (size_t)b * SS;

  int w = tid >> 6, l = tid & 63;
  int wr = w >> 2, wc = w & 3;          // 2x4 wave grid
  int arow = wr * 16 + (l & 15);        // A-frag p row 0..31
  unsigned asw = ((unsigned)(arow & 7)) << 4;
  int lk8 = (l >> 4) << 3;              // k sub-offset (0,8,16,24)
  int qcl = wc * 64 + (l & 15);         // B-frag q col base (plus cf*16)

  f32x4 acc[4];
#pragma unroll
  for (int i = 0; i < 4; ++i) acc[i] = (f32x4){0.f, 0.f, 0.f, 0.f};

  char* AshB = (char*)Ash;
  char* AslB = (char*)Asl;
  char* BshB = (char*)Bsh;
  char* BslB = (char*)Bsl;

  for (int k0 = 0; k0 < HH; k0 += 64) {
    // stage A: 32 p-rows x 64 h (256 threads, ushort8 each)
    if (tid < 256) {
      int row = tid >> 3;
      int k8 = (tid & 7) << 3;
      unsigned off = ((unsigned)(row * 128 + k8 * 2)) ^ (((unsigned)(row & 7)) << 4);
      size_t g = (bS + p0 + row) * HH + k0 + k8;
      *(ushort8*)(AshB + off) = *(const ushort8*)(Ah_g + g);
      *(ushort8*)(AslB + off) = *(const ushort8*)(Al_g + g);
    }
    // stage B: 256 q-rows x 64 h
#pragma unroll
    for (int i = 0; i < 4; ++i) {
      int idx = tid + i * 512;
      int row = idx >> 3;
      int k8 = (idx & 7) << 3;
      unsigned off = ((unsigned)(row * 128 + k8 * 2)) ^ (((unsigned)(row & 7)) << 4);
      size_t g = (bS + q0 + row) * HH + k0 + k8;
      *(ushort8*)(BshB + off) = *(const ushort8*)(Bh_g + g);
      *(ushort8*)(BslB + off) = *(const ushort8*)(Bl_g + g);
    }
    __syncthreads();
#pragma unroll
    for (int kc = 0; kc < 64; kc += 32) {
      int ak = kc + lk8;
      unsigned aoff = ((unsigned)(arow * 128 + ak * 2)) ^ asw;
      bf16x8 ah = *(const bf16x8*)(AshB + aoff);
      bf16x8 al = *(const bf16x8*)(AslB + aoff);
#pragma unroll
      for (int cf = 0; cf < 4; ++cf) {
        int r = qcl + cf * 16;
        unsigned boff = ((unsigned)(r * 128 + ak * 2)) ^ (((unsigned)(r & 7)) << 4);
        bf16x8 bh = *(const bf16x8*)(BshB + boff);
        bf16x8 bl = *(const bf16x8*)(BslB + boff);
        acc[cf] = __builtin_amdgcn_mfma_f32_16x16x32_bf16(ah, bh, acc[cf], 0, 0, 0);
        acc[cf] = __builtin_amdgcn_mfma_f32_16x16x32_bf16(ah, bl, acc[cf], 0, 0, 0);
        acc[cf] = __builtin_amdgcn_mfma_f32_16x16x32_bf16(al, bh, acc[cf], 0, 0, 0);
      }
    }
    __syncthreads();
  }

  // epilogue: + sp + sq, mask, store U
  int crow = wr * 16 + ((l >> 4) << 2);  // + j
  float spr[4], mpr[4];
#pragma unroll
  for (int j = 0; j < 4; ++j) {
    spr[j] = spv[bS + p0 + crow + j];
    mpr[j] = m1[bS + p0 + crow + j];
  }
#pragma unroll
  for (int cf = 0; cf < 4; ++cf) {
    int q = q0 + qcl + cf * 16;
    float sqc = sqv[bS + q];
    float mqc = m2[bS + q];
#pragma unroll
    for (int j = 0; j < 4; ++j) {
      int p = p0 + crow + j;
      float v = acc[cf][j] + spr[j] + sqc;
      if (mpr[j] * mqc < 0.5f) v = NEG_BIG;
      U[(bS + p) * SS + q] = v;
    }
  }
}

// ------------------------------------------------------------------
// K2: row softmax stats (axis=2, over q)
// ------------------------------------------------------------------
__global__ __launch_bounds__(256) void k_rowstats(
    const float* __restrict__ U, float* __restrict__ rowmax, float* __restrict__ rowinv) {
  __shared__ float redm[4];
  __shared__ float reds[4];
  int row = blockIdx.x;
  int tid = threadIdx.x;
  const float* u = U + (size_t)row * SS;
  float4 v1 = ((const float4*)u)[tid];
  float4 v2 = ((const float4*)u)[tid + 256];
  float m = fmaxf(fmaxf(fmaxf(v1.x, v1.y), fmaxf(v1.z, v1.w)),
                  fmaxf(fmaxf(v2.x, v2.y), fmaxf(v2.z, v2.w)));
#pragma unroll
  for (int off = 32; off > 0; off >>= 1) m = fmaxf(m, __shfl_down(m, off, 64));
  if ((tid & 63) == 0) redm[tid >> 6] = m;
  __syncthreads();
  m = fmaxf(fmaxf(redm[0], redm[1]), fmaxf(redm[2], redm[3]));
  float s = __expf(v1.x - m) + __expf(v1.y - m) + __expf(v1.z - m) + __expf(v1.w - m)
          + __expf(v2.x - m) + __expf(v2.y - m) + __expf(v2.z - m) + __expf(v2.w - m);
#pragma unroll
  for (int off = 32; off > 0; off >>= 1) s += __shfl_down(s, off, 64);
  if ((tid & 63) == 0) reds[tid >> 6] = s;
  __syncthreads();
  if (tid == 0) {
    float st = reds[0] + reds[1] + reds[2] + reds[3];
    rowmax[row] = m;
    rowinv[row] = 1.0f / st;
  }
}

// ------------------------------------------------------------------
// K3a/K3b: column softmax stats (axis=1, over p)
// ------------------------------------------------------------------
__global__ __launch_bounds__(256) void k_colpart(
    const float* __restrict__ U, float* __restrict__ pm, float* __restrict__ ps) {
  int q = blockIdx.x * 256 + threadIdx.x;
  int pc = blockIdx.y;
  int b = blockIdx.z;
  const float* u = U + ((size_t)b * SS + pc * 128) * SS + q;
  float m = -INFINITY, s = 0.f;
  for (int p = 0; p < 128; ++p) {
    float x = u[(size_t)p * SS];
    float nm = fmaxf(m, x);
    s = s * __expf(m - nm) + __expf(x - nm);
    m = nm;
  }
  int o = (pc * BB + b) * SS + q;
  pm[o] = m;
  ps[o] = s;
}

__global__ __launch_bounds__(256) void k_colcomb(
    const float* __restrict__ pm, const float* __restrict__ ps,
    float* __restrict__ colmax, float* __restrict__ colinv) {
  int i = blockIdx.x * 256 + threadIdx.x;
  float m = -INFINITY;
#pragma unroll
  for (int pc = 0; pc < 16; ++pc) m = fmaxf(m, pm[(size_t)pc * BB * SS + i]);
  float s = 0.f;
#pragma unroll
  for (int pc = 0; pc < 16; ++pc)
    s += ps[(size_t)pc * BB * SS + i] * __expf(pm[(size_t)pc * BB * SS + i] - m);
  colmax[i] = m;
  colinv[i] = 1.0f / s;
}

// ------------------------------------------------------------------
// MFMA level kernels: Out[r,h] = sum_k exp(U - max) * E[k,h]
// ROUND 11: round-9 geometry (512 thr, 32-row, 72KB, 2 blk/CU — proven
// 103us) + T14 async-STAGE: next tile's B+U loads issued into registers
// between the barriers, in flight during the MFMA phase. Write phase
// becomes pure VALU+ds_write (global latency hidden under MFMA).
// ------------------------------------------------------------------
template <int LEVEL>
__global__ __launch_bounds__(512, 4) void k_level(
    const float* __restrict__ U,
    const ushort_t* __restrict__ B0h, const ushort_t* __restrict__ B0l,
    const ushort_t* __restrict__ B1h, const ushort_t* __restrict__ B1l,
    const float* __restrict__ rowmax, const float* __restrict__ rowinv,
    const float* __restrict__ colmax, const float* __restrict__ colinv,
    const float* __restrict__ Eq, const float* __restrict__ Ep,
    float* __restrict__ A1w, float* __restrict__ B1w,
    float* __restrict__ out) {
  __shared__ ushort_t Ph[32 * 64];    // 4 KB
  __shared__ ushort_t Pl[32 * 64];    // 4 KB
  __shared__ ushort_t Bsh[256 * 64];  // 32 KB
  __shared__ ushort_t Bsl[256 * 64];  // 32 KB
  int b = blockIdx.z;
  int mode = blockIdx.y;
  int r0 = blockIdx.x << 5;
  int tid = threadIdx.x;
  size_t bS = (size_t)b * SS;
  const float* Ub = U + bS * SS;
  const ushort_t* Bh = (mode == 0 ? B0h : B1h) + (size_t)b * HH * SS;
  const ushort_t* Bl = (mode == 0 ? B0l : B1l) + (size_t)b * HH * SS;

  int srow0 = tid >> 4;           // mode0: p row 0..31
  int sc40 = (tid & 15) << 2;     // mode0: q (k) 0..60
  int srow1 = tid >> 3;           // mode1: p (k) 0..63
  int sc41 = (tid & 7) << 2;      // mode1: q col 0..28
  float rm = 0.f;
  float4 cm4;
  if (mode == 0) rm = rowmax[bS + r0 + srow0];
  else cm4 = *(const float4*)(colmax + bS + r0 + sc41);

  int w = tid >> 6, l = tid & 63;
  int wr = w >> 2, wc = w & 3;
  int arow = wr * 16 + (l & 15);
  unsigned asw = ((unsigned)(arow & 7)) << 4;
  int lk8 = (l >> 4) << 3;
  int hcol = wc * 64 + (l & 15);

  f32x4 acc[4];
#pragma unroll
  for (int i = 0; i < 4; ++i) acc[i] = (f32x4){0.f, 0.f, 0.f, 0.f};

  char* PhB = (char*)Ph;
  char* PlB = (char*)Pl;
  char* BhB = (char*)Bsh;
  char* BlB = (char*)Bsl;

  // T14 prefetch registers (B panel chunk + U row chunk)
  ushort8 bhr[4], blr[4];
  float4 u4p;

  // prologue: issue loads for k0 = 0
#pragma unroll
  for (int i = 0; i < 4; ++i) {
    int idx = tid + i * 512;
    int h = idx >> 3;
    int k8 = (idx & 7) << 3;
    bhr[i] = *(const ushort8*)(Bh + (size_t)h * SS + k8);
    blr[i] = *(const ushort8*)(Bl + (size_t)h * SS + k8);
  }
  u4p = (mode == 0)
      ? *(const float4*)(Ub + (size_t)(r0 + srow0) * SS + sc40)
      : *(const float4*)(Ub + (size_t)srow1 * SS + r0 + sc41);

  for (int k0 = 0; k0 < SS; k0 += 64) {
    // ---- write phase: registers -> swizzled LDS (no global loads) ----
#pragma unroll
    for (int i = 0; i < 4; ++i) {
      int idx = tid + i * 512;
      int h = idx >> 3;
      int k8 = (idx & 7) << 3;
      unsigned off = ((unsigned)(h * 128 + k8 * 2)) ^ (((unsigned)(h & 7)) << 4);
      *(ushort8*)(BhB + off) = bhr[i];
      *(ushort8*)(BlB + off) = blr[i];
    }
    if (mode == 0) {
      ushort4 h4, l4;
      ushort_t hh, ll;
      bsplit(__expf(u4p.x - rm), hh, ll); h4.x = hh; l4.x = ll;
      bsplit(__expf(u4p.y - rm), hh, ll); h4.y = hh; l4.y = ll;
      bsplit(__expf(u4p.z - rm), hh, ll); h4.z = hh; l4.z = ll;
      bsplit(__expf(u4p.w - rm), hh, ll); h4.w = hh; l4.w = ll;
      unsigned off = ((unsigned)(srow0 * 128 + sc40 * 2)) ^ (((unsigned)(srow0 & 7)) << 4);
      *(ushort4*)(PhB + off) = h4;
      *(ushort4*)(PlB + off) = l4;
    } else {
      float e[4] = {__expf(u4p.x - cm4.x), __expf(u4p.y - cm4.y),
                    __expf(u4p.z - cm4.z), __expf(u4p.w - cm4.w)};
#pragma unroll
      for (int j = 0; j < 4; ++j) {
        ushort_t hh, ll;
        bsplit(e[j], hh, ll);
        int rr = sc41 + j;
        unsigned off = ((unsigned)(rr * 128 + srow1 * 2)) ^ (((unsigned)(rr & 7)) << 4);
        *(ushort_t*)(PhB + off) = hh;
        *(ushort_t*)(PlB + off) = ll;
      }
    }
    __syncthreads();
    // ---- prefetch next tile (in flight during MFMA phase) ----
    int kn = k0 + 64;
    if (kn < SS) {
#pragma unroll
      for (int i = 0; i < 4; ++i) {
        int idx = tid + i * 512;
        int h = idx >> 3;
        int k8 = (idx & 7) << 3;
        bhr[i] = *(const ushort8*)(Bh + (size_t)h * SS + kn + k8);
        blr[i] = *(const ushort8*)(Bl + (size_t)h * SS + kn + k8);
      }
      u4p = (mode == 0)
          ? *(const float4*)(Ub + (size_t)(r0 + srow0) * SS + kn + sc40)
          : *(const float4*)(Ub + (size_t)(kn + srow1) * SS + r0 + sc41);
    }
    // ---- MFMA phase: 2 K-chunks of 32 ----
#pragma unroll
    for (int kc = 0; kc < 64; kc += 32) {
      int ak = kc + lk8;
      unsigned aoff = ((unsigned)(arow * 128 + ak * 2)) ^ asw;
      bf16x8 ah = *(const bf16x8*)(PhB + aoff);
      bf16x8 al = *(const bf16x8*)(PlB + aoff);
#pragma unroll
      for (int cf = 0; cf < 4; ++cf) {
        int h = hcol + cf * 16;
        unsigned boff = ((unsigned)(h * 128 + ak * 2)) ^ (((unsigned)(h & 7)) << 4);
        bf16x8 bh = *(const bf16x8*)(BhB + boff);
        bf16x8 bl = *(const bf16x8*)(BlB + boff);
        acc[cf] = __builtin_amdgcn_mfma_f32_16x16x32_bf16(ah, bh, acc[cf], 0, 0, 0);
        acc[cf] = __builtin_amdgcn_mfma_f32_16x16x32_bf16(ah, bl, acc[cf], 0, 0, 0);
        acc[cf] = __builtin_amdgcn_mfma_f32_16x16x32_bf16(al, bh, acc[cf], 0, 0, 0);
      }
    }
    __syncthreads();
  }

  int crow = wr * 16 + ((l >> 4) << 2);
  if (LEVEL == 1) {
    const float* inv = mode == 0 ? rowinv : colinv;
    float* Out = mode == 0 ? A1w : B1w;
#pragma unroll
    for (int j = 0; j < 4; ++j) {
      int rr = r0 + crow + j;
      float sc = inv[bS + rr];
#pragma unroll
      for (int cf = 0; cf < 4; ++cf) {
        int h = hcol + cf * 16;
        Out[(bS + rr) * HH + h] = acc[cf][j] * sc;
      }
    }
  } else {
    if (mode == 0) {
      float* Gqp = out + GSEG;
#pragma unroll
      for (int j = 0; j < 4; ++j) {
        int rr = r0 + crow + j;
        float sc = rowinv[bS + rr];
#pragma unroll
        for (int cf = 0; cf < 4; ++cf) {
          int h = hcol + cf * 16;
          size_t eidx = (bS + rr) * HH + h;
          float a2 = acc[cf][j] * sc;
          float ep = Ep[eidx];
          float a1 = A1w[eidx];
          float* g = Gqp + (bS + rr) * (size_t)(5 * HH) + h;
          g[0 * HH] = ep;
          g[1 * HH] = a1;
          g[2 * HH] = a2;
          g[3 * HH] = ep * a1;
          g[4 * HH] = ep * a2;
        }
      }
    } else {
#pragma unroll
      for (int j = 0; j < 4; ++j) {
        int rr = r0 + crow + j;
        float sc = colinv[bS + rr];
#pragma unroll
        for (int cf = 0; cf < 4; ++cf) {
          int h = hcol + cf * 16;
          size_t eidx = (bS + rr) * HH + h;
          float b2 = acc[cf][j] * sc;
          float eq = Eq[eidx];
          float b1 = B1w[eidx];
          float* g = out + (bS + rr) * (size_t)(5 * HH) + h;
          g[0 * HH] = eq;
          g[1 * HH] = b1;
          g[2 * HH] = b2;
          g[3 * HH] = eq * b1;
          g[4 * HH] = eq * b2;
        }
      }
    }
  }
}

// ------------------------------------------------------------------
extern "C" void kernel_launch(void* const* d_in, const int* in_sizes, int n_in,
                              void* d_out, int out_size, void* d_ws, size_t ws_size,
                              hipStream_t stream) {
  const float* Eq = (const float*)d_in[0];
  const float* Ep = (const float*)d_in[1];
  const float* m1 = (const float*)d_in[2];
  const float* m2 = (const float*)d_in[3];
  const float* W  = (const float*)d_in[4];
  float* out = (float*)d_out;

  // workspace layout (~96 MB — matches the HW-proven round-3/6/9 footprint)
  float* ws     = (float*)d_ws;
  float* U      = ws;                              // B*S*S fp32 (64 MB)
  float* rowmax = U + (size_t)BB * SS * SS;
  float* rowinv = rowmax + BB * SS;
  float* colmax = rowinv + BB * SS;
  float* colinv = colmax + BB * SS;
  float* spv    = colinv + BB * SS;
  float* sqv    = spv + BB * SS;
  float* A1w    = sqv + BB * SS;                   // B*S*H fp32 (8 MB)
  float* B1w    = A1w + NT;                        // B*S*H fp32 (8 MB)
  ushort_t* EqTh = (ushort_t*)(B1w + NT);          // 4 x (B*H*S) bf16 (16 MB)
  ushort_t* EqTl = EqTh + NT;
  ushort_t* EpTh = EqTl + NT;
  ushort_t* EpTl = EpTh + NT;
  // Row-major split tensors alias A1w/B1w: consumed only by k_trim, which
  // runs before anything writes A1w/B1w. EqRh+EqRl (8MB) == A1w's 8MB.
  ushort_t* EqRh = (ushort_t*)A1w;
  ushort_t* EqRl = EqRh + NT;
  ushort_t* ApRh = (ushort_t*)B1w;
  ushort_t* ApRl = ApRh + NT;
  // pm/ps also alias A1w: written by k_colpart AFTER k_trim (EqR dead),
  // dead after k_colcomb, before k_level<1> writes A1w.
  float* pm     = A1w;
  float* ps     = pm + 16 * BB * SS;
  // A1T/B1T alias EqT/EpT storage: EqT/EpT dead after k_level<1>
  ushort_t* A1Th = EqTh;
  ushort_t* A1Tl = EqTl;
  ushort_t* B1Th = EpTh;
  ushort_t* B1Tl = EpTl;

  dim3 tcg(SS / 64, HH / 64, BB);

  k_rowdots<<<2 * BB * SS / 4, 256, 0, stream>>>(Eq, Ep, W, sqv, spv);
  k_rc<<<(int)(NT / 2048), 256, 0, stream>>>(Eq, nullptr, EqRh, EqRl);
  k_rc<<<(int)(NT / 2048), 256, 0, stream>>>(Ep, W + 2 * HH, ApRh, ApRl);
  k_tc<<<tcg, 256, 0, stream>>>(Eq, EqTh, EqTl);
  k_tc<<<tcg, 256, 0, stream>>>(Ep, EpTh, EpTl);
  k_trim<<<dim3(SS / 256, SS / 32, BB), 512, 0, stream>>>(
      ApRh, ApRl, EqRh, EqRl, m1, m2, spv, sqv, U);
  k_rowstats<<<BB * SS, 256, 0, stream>>>(U, rowmax, rowinv);
  k_colpart<<<dim3(SS / 256, 16, BB), 256, 0, stream>>>(U, pm, ps);
  k_colcomb<<<BB * SS / 256, 256, 0, stream>>>(pm, ps, colmax, colinv);
  k_level<1><<<dim3(SS / 32, 2, BB), 512, 0, stream>>>(
      U, EqTh, EqTl, EpTh, EpTl, rowmax, rowinv, colmax, colinv,
      Eq, Ep, A1w, B1w, out);
  k_tc<<<tcg, 256, 0, stream>>>(A1w, A1Th, A1Tl);
  k_tc<<<tcg, 256, 0, stream>>>(B1w, B1Th, B1Tl);
  k_level<2><<<dim3(SS / 32, 2, BB), 512, 0, stream>>>(
      U, B1Th, B1Tl, A1Th, A1Tl, rowmax, rowinv, colmax, colinv,
      Eq, Ep, A1w, B1w, out);
}